// Round 1
// baseline (452.256 us; speedup 1.0000x reference)
//
#include <hip/hip_runtime.h>
#include <math.h>

// LSTM: N=32768 seqs, T=600, H=5, input dim 1.
// Layout: 2 lanes per sequence. Even lane (half=0): i-gates rows 0..4, g-gates rows 10..14.
//         Odd lane (half=1):  f-gates rows 5..9,  o-gates rows 15..19.
// Both lanes redundantly hold full h[5], c[5] (avoids h-broadcast; issue cost is wave-wide anyway).
// Block = 64 threads = 1 wave = 32 sequences; grid = 1024 blocks -> 1 wave per SIMD chip-wide.

#define LOG2E 1.44269504088896340736f

constexpr int H_ = 5;
constexpr int T_ = 600;
constexpr int SEQ_PER_BLOCK = 32;
constexpr int TTILE = 64;
constexpr int LDS_STRIDE = 68; // floats; 68*4=272 bytes, multiple of 16 (b128-aligned), 68%32=4 -> mild 4-way conflict only

__device__ __forceinline__ float fast_rcp(float v) { return __builtin_amdgcn_rcpf(v); }

__global__ __launch_bounds__(64, 1) void lstm_kernel(
    const float* __restrict__ x,
    const float* __restrict__ w_ih,   // (20,1)
    const float* __restrict__ w_hh,   // (20,5)
    const float* __restrict__ b_ih,   // (20,)
    const float* __restrict__ b_hh,   // (20,)
    const float* __restrict__ fc_w,   // (15,5)
    const float* __restrict__ fc_b,   // (15,)
    const float* __restrict__ out_w,  // (1,15)
    const float* __restrict__ out_b,  // (1,)
    float* __restrict__ out)          // (N,1)
{
    __shared__ float xs[SEQ_PER_BLOCK * LDS_STRIDE];

    const int lane = threadIdx.x;     // 0..63
    const int s    = lane >> 1;       // local sequence 0..31
    const int half = lane & 1;        // 0: i/g rows, 1: f/o rows
    const int seq  = blockIdx.x * SEQ_PER_BLOCK + s;

    // ---- per-lane weights: 10 gate rows ----
    float wih[10], bb[10], whh[10][5];
#pragma unroll
    for (int j = 0; j < 10; ++j) {
        const int row = (j < 5) ? (half * 5 + j) : (10 + half * 5 + (j - 5));
        wih[j] = w_ih[row];
        bb[j]  = b_ih[row] + b_hh[row];
#pragma unroll
        for (int k = 0; k < 5; ++k) whh[j][k] = w_hh[row * 5 + k];
    }
    // activation constants for j>=5: half0 -> tanh (y=2*sig(2x)-1), half1 -> sigmoid
    const float S_hi = half ? -LOG2E : -2.0f * LOG2E;
    const float A_hi = half ? 1.0f : 2.0f;
    const float B_hi = half ? 0.0f : -1.0f;

    float h[5] = {0.f, 0.f, 0.f, 0.f, 0.f};
    float c[5] = {0.f, 0.f, 0.f, 0.f, 0.f};

    const float* xblk = x + (size_t)(blockIdx.x * SEQ_PER_BLOCK) * T_;

    auto step = [&](float xt) {
        float act[10];
#pragma unroll
        for (int j = 0; j < 10; ++j) {
            float g = fmaf(xt, wih[j], bb[j]);
#pragma unroll
            for (int k = 0; k < 5; ++k) g = fmaf(h[k], whh[j][k], g);
            const float S = (j < 5) ? (-LOG2E) : S_hi;
            const float r = fast_rcp(1.0f + exp2f(g * S));
            act[j] = (j < 5) ? r : fmaf(r, A_hi, B_hi);
        }
        float oth[10];
#pragma unroll
        for (int j = 0; j < 10; ++j) oth[j] = __shfl_xor(act[j], 1, 64);
#pragma unroll
        for (int k = 0; k < 5; ++k) {
            // half0: act=i,g  oth=f,o   |   half1: act=f,o  oth=i,g
            const float p  = half ? (oth[k] * oth[k + 5]) : (act[k] * act[k + 5]); // i*g
            const float fg = half ? act[k] : oth[k];                               // f
            const float og = half ? act[k + 5] : oth[k + 5];                       // o
            c[k] = fmaf(fg, c[k], p);
            const float rr = fast_rcp(1.0f + exp2f(c[k] * (-2.0f * LOG2E)));
            const float tc = fmaf(rr, 2.0f, -1.0f); // tanh(c)
            h[k] = og * tc;
        }
    };

    const int rrow = lane >> 4;         // 0..3
    const int ccol = (lane & 15) << 2;  // 0,4,...,60

    for (int t0 = 0; t0 < T_; t0 += TTILE) {
        __syncthreads();
        // stage 32 rows x up-to-64 cols, coalesced float4 loads
#pragma unroll
        for (int it = 0; it < 8; ++it) {
            const int r = it * 4 + rrow;
            if (t0 + ccol < T_) {
                const float4 v = *(const float4*)(xblk + (size_t)r * T_ + (t0 + ccol));
                *(float4*)&xs[r * LDS_STRIDE + ccol] = v;
            }
        }
        __syncthreads();

        const int steps = min(TTILE, T_ - t0); // 64 or 24, both %4==0
        const float* xr = &xs[s * LDS_STRIDE];
        for (int tt = 0; tt < steps; tt += 4) {
            const float4 xv = *(const float4*)&xr[tt];
            step(xv.x);
            step(xv.y);
            step(xv.z);
            step(xv.w);
        }
    }

    // ---- head: hid = h@fc_w.T + fc_b ; out = sigmoid(hid@out_w.T + out_b) ----
    if (half == 0) {
        float acc = out_b[0];
#pragma unroll
        for (int j = 0; j < 15; ++j) {
            float hid = fc_b[j];
#pragma unroll
            for (int k = 0; k < 5; ++k) hid = fmaf(h[k], fc_w[j * 5 + k], hid);
            acc = fmaf(hid, out_w[j], acc);
        }
        out[seq] = fast_rcp(1.0f + exp2f(-acc * LOG2E));
    }
}

extern "C" void kernel_launch(void* const* d_in, const int* in_sizes, int n_in,
                              void* d_out, int out_size, void* d_ws, size_t ws_size,
                              hipStream_t stream) {
    const float* x    = (const float*)d_in[0];
    const float* w_ih = (const float*)d_in[1];
    const float* w_hh = (const float*)d_in[2];
    const float* b_ih = (const float*)d_in[3];
    const float* b_hh = (const float*)d_in[4];
    const float* fc_w = (const float*)d_in[5];
    const float* fc_b = (const float*)d_in[6];
    const float* out_w = (const float*)d_in[7];
    const float* out_b = (const float*)d_in[8];
    float* out = (float*)d_out;

    const int N = in_sizes[0] / T_;            // 32768
    const int grid = N / SEQ_PER_BLOCK;        // 1024 blocks of 1 wave
    hipLaunchKernelGGL(lstm_kernel, dim3(grid), dim3(64), 0, stream,
                       x, w_ih, w_hh, b_ih, b_hh, fc_w, fc_b, out_w, out_b, out);
}

// Round 2
// 316.419 us; speedup vs baseline: 1.4293x; 1.4293x over previous
//
#include <hip/hip_runtime.h>
#include <math.h>

// LSTM: N=32768 seqs, T=600, H=5, input dim 1.
// 2 lanes per sequence. Even lane (half=0): i rows 0..4 (.x), g rows 10..14 (.y).
//                       Odd lane (half=1):  f rows 5..9 (.x), o rows 15..19 (.y).
// Cross-lane exchange via DPP quad_perm swap (lane^1) — VALU op, no LDS pipe.
// Gate math in float2 ext-vectors to encourage v_pk_fma_f32.
// Block = 64 threads = 1 wave = 32 sequences; grid = 1024 blocks -> 1 wave/SIMD chip-wide.

#define LOG2E 1.44269504088896340736f

typedef float v2f __attribute__((ext_vector_type(2)));

constexpr int T_ = 600;
constexpr int SEQ_PER_BLOCK = 32;
constexpr int TTILE = 64;
constexpr int LDS_STRIDE = 68;

__device__ __forceinline__ float fast_rcp(float v) { return __builtin_amdgcn_rcpf(v); }
__device__ __forceinline__ float fast_exp2(float v) { return __builtin_amdgcn_exp2f(v); }

// swap with lane^1 via DPP quad_perm [1,0,3,2] = 0xB1; full-rate VALU, no lgkm wait
__device__ __forceinline__ float dpp_swap1(float v) {
    int r = __builtin_amdgcn_update_dpp(0, __float_as_int(v), 0xB1, 0xF, 0xF, true);
    return __int_as_float(r);
}

__global__ __launch_bounds__(64, 1) void lstm_kernel(
    const float* __restrict__ x,
    const float* __restrict__ w_ih,   // (20,1)
    const float* __restrict__ w_hh,   // (20,5)
    const float* __restrict__ b_ih,   // (20,)
    const float* __restrict__ b_hh,   // (20,)
    const float* __restrict__ fc_w,   // (15,5)
    const float* __restrict__ fc_b,   // (15,)
    const float* __restrict__ out_w,  // (1,15)
    const float* __restrict__ out_b,  // (1,)
    float* __restrict__ out)          // (N,1)
{
    __shared__ float xs[SEQ_PER_BLOCK * LDS_STRIDE];

    const int lane = threadIdx.x;     // 0..63
    const int s    = lane >> 1;       // local sequence 0..31
    const int half = lane & 1;        // 0: i/g rows, 1: f/o rows
    const int seq  = blockIdx.x * SEQ_PER_BLOCK + s;

    // ---- per-lane weights: 5 row-pairs (lo = sigmoid-row, hi = tanh/sigmoid-row) ----
    v2f wih[5], bb[5], whh[5][5];
#pragma unroll
    for (int p = 0; p < 5; ++p) {
        const int rlo = half * 5 + p;        // i (h0) or f (h1)
        const int rhi = 10 + half * 5 + p;   // g (h0) or o (h1)
        wih[p] = (v2f){ w_ih[rlo], w_ih[rhi] };
        bb[p]  = (v2f){ b_ih[rlo] + b_hh[rlo], b_ih[rhi] + b_hh[rhi] };
#pragma unroll
        for (int k = 0; k < 5; ++k)
            whh[p][k] = (v2f){ w_hh[rlo * 5 + k], w_hh[rhi * 5 + k] };
    }
    // activation constants: .x always sigmoid; .y = tanh (h0) / sigmoid (h1)
    const v2f Sv = (v2f){ -LOG2E, half ? -LOG2E : -2.0f * LOG2E };
    const v2f Av = (v2f){ 1.0f,   half ? 1.0f   : 2.0f };
    const v2f Bv = (v2f){ 0.0f,   half ? 0.0f   : -1.0f };

    float h[5] = {0.f, 0.f, 0.f, 0.f, 0.f};
    float c[5] = {0.f, 0.f, 0.f, 0.f, 0.f};

    const float* xblk = x + (size_t)(blockIdx.x * SEQ_PER_BLOCK) * T_;

    auto step = [&](float xt) {
        // ---- gates: g[p] = bb + xt*wih + sum_k h[k]*whh[p][k]  (v_pk_fma path) ----
        v2f g[5];
        const v2f xv = (v2f){ xt, xt };
#pragma unroll
        for (int p = 0; p < 5; ++p) g[p] = bb[p] + xv * wih[p];
#pragma unroll
        for (int k = 0; k < 5; ++k) {
            const v2f hk = (v2f){ h[k], h[k] };
#pragma unroll
            for (int p = 0; p < 5; ++p) g[p] += hk * whh[p][k];
        }
        // ---- activations: r = 1/(1+2^(g*S)); act = r*A + B ----
        v2f act[5];
#pragma unroll
        for (int p = 0; p < 5; ++p) {
            const v2f t = g[p] * Sv;
            const float ex = 1.0f + fast_exp2(t.x);
            const float ey = 1.0f + fast_exp2(t.y);
            const float inv = fast_rcp(ex * ey);    // paired rcp: 1 trans for 2 recips
            const v2f r = (v2f){ ey * inv, ex * inv };
            act[p] = r * Av + Bv;
        }
        // ---- exchange with partner lane (DPP, full-rate VALU) ----
        v2f oact[5];
#pragma unroll
        for (int p = 0; p < 5; ++p)
            oact[p] = (v2f){ dpp_swap1(act[p].x), dpp_swap1(act[p].y) };

        // ---- canonical gates + state update ----
        float d[5], ov[5];
#pragma unroll
        for (int k = 0; k < 5; ++k) {
            const float iv = half ? oact[k].x : act[k].x;
            const float fv = half ? act[k].x  : oact[k].x;
            const float gv = half ? oact[k].y : act[k].y;
            ov[k]          = half ? act[k].y  : oact[k].y;
            c[k] = fmaf(fv, c[k], iv * gv);
            d[k] = 1.0f + fast_exp2(c[k] * (-2.0f * LOG2E));
        }
        // paired rcps for tanh(c): (0,1), (2,3), (4)
        {
            const float i01 = fast_rcp(d[0] * d[1]);
            const float i23 = fast_rcp(d[2] * d[3]);
            const float r0 = d[1] * i01, r1 = d[0] * i01;
            const float r2 = d[3] * i23, r3 = d[2] * i23;
            const float r4 = fast_rcp(d[4]);
            h[0] = ov[0] * fmaf(r0, 2.0f, -1.0f);
            h[1] = ov[1] * fmaf(r1, 2.0f, -1.0f);
            h[2] = ov[2] * fmaf(r2, 2.0f, -1.0f);
            h[3] = ov[3] * fmaf(r3, 2.0f, -1.0f);
            h[4] = ov[4] * fmaf(r4, 2.0f, -1.0f);
        }
    };

    const int rrow = lane >> 4;         // 0..3
    const int ccol = (lane & 15) << 2;  // 0,4,...,60

    for (int t0 = 0; t0 < T_; t0 += TTILE) {
        __syncthreads();
#pragma unroll
        for (int it = 0; it < 8; ++it) {
            const int r = it * 4 + rrow;
            if (t0 + ccol < T_) {
                const float4 v = *(const float4*)(xblk + (size_t)r * T_ + (t0 + ccol));
                *(float4*)&xs[r * LDS_STRIDE + ccol] = v;
            }
        }
        __syncthreads();

        const int steps = min(TTILE, T_ - t0); // 64 or 24
        const float* xr = &xs[s * LDS_STRIDE];
        for (int tt = 0; tt < steps; tt += 4) {
            const float4 xv4 = *(const float4*)&xr[tt];
            step(xv4.x);
            step(xv4.y);
            step(xv4.z);
            step(xv4.w);
        }
    }

    // ---- head: hid = h@fc_w.T + fc_b ; out = sigmoid(hid@out_w.T + out_b) ----
    if (half == 0) {
        float acc = out_b[0];
#pragma unroll
        for (int j = 0; j < 15; ++j) {
            float hid = fc_b[j];
#pragma unroll
            for (int k = 0; k < 5; ++k) hid = fmaf(h[k], fc_w[j * 5 + k], hid);
            acc = fmaf(hid, out_w[j], acc);
        }
        out[seq] = fast_rcp(1.0f + fast_exp2(-acc * LOG2E));
    }
}

extern "C" void kernel_launch(void* const* d_in, const int* in_sizes, int n_in,
                              void* d_out, int out_size, void* d_ws, size_t ws_size,
                              hipStream_t stream) {
    const float* x    = (const float*)d_in[0];
    const float* w_ih = (const float*)d_in[1];
    const float* w_hh = (const float*)d_in[2];
    const float* b_ih = (const float*)d_in[3];
    const float* b_hh = (const float*)d_in[4];
    const float* fc_w = (const float*)d_in[5];
    const float* fc_b = (const float*)d_in[6];
    const float* out_w = (const float*)d_in[7];
    const float* out_b = (const float*)d_in[8];
    float* out = (float*)d_out;

    const int N = in_sizes[0] / T_;            // 32768
    const int grid = N / SEQ_PER_BLOCK;        // 1024 blocks of 1 wave
    hipLaunchKernelGGL(lstm_kernel, dim3(grid), dim3(64), 0, stream,
                       x, w_ih, w_hh, b_ih, b_hh, fc_w, fc_b, out_w, out_b, out);
}